// Round 1
// baseline (1753.868 us; speedup 1.0000x reference)
//
#include <hip/hip_runtime.h>

// VanillaRNN: BATCH=1024, SEQ=512, HID=512, OUT=10
// h <- tanh(W_hh @ h + W_hx x_t + b_h), 512 steps, then y = W_yh h + b_y.
//
// Round 5: attack the DS pipe + barrier structure R4's counters exposed
// (MfmaUtil 8.6%, VALUBusy 9.2%, ~3100 cyc/step of serialized LDS reads):
//   * phase-2 W (kk 12..15) now loads straight from global (L1/L2-resident,
//     identical across steps and across the 8 CUs of an XCD) -> LDS read
//     traffic halves (256KB -> 128KB/step) and moves to the VMEM pipe,
//     which overlaps DS + MFMA.
//   * HB double-buffered (LDS 144KB -> 32KB) -> ONE __syncthreads per step
//     instead of two (no write-after-read hazard on h).
//   * x/Whx/bh loads issued at step top (latency hides under MFMA phase);
//     anti-LICM asm clobbers keep them (and the W-tail pointer) from being
//     hoisted into 96 registers, which would blow the 256-reg/wave budget.
//
// ws: [0,1MB) hG (final h, frag-blocked) | [2MB,2.5MB) W A-frags.

#define BATCH 1024
#define SEQT  512
#define HID   512
#define OUTD  10
#define KR    12   // kk-blocks (of K=32) in registers: K=384
#define NKK   16

typedef _Float16 f16;
typedef _Float16 f16x8 __attribute__((ext_vector_type(8)));
typedef _Float16 f16x4 __attribute__((ext_vector_type(4)));
typedef float    f32x4 __attribute__((ext_vector_type(4)));

// W_hh fp32 [H][H] -> fp16 A-fragment layout:
// entry ((g*4+mt)*16+kk)*64+lane = f16x8 of A[m][k],
// m = g*64+mt*16+(lane&15), k = kk*32+((lane>>4)&3)*8+j.
__global__ void wconv_kernel(const float* __restrict__ Whh, f16* __restrict__ frag) {
    int id = blockIdx.x * blockDim.x + threadIdx.x;   // 0..32767
    int lane = id & 63;
    int kk   = (id >> 6) & 15;
    int mt   = (id >> 10) & 3;
    int g    = id >> 12;
    int m = g * 64 + mt * 16 + (lane & 15);
    int k = kk * 32 + ((lane >> 4) & 3) * 8;
    const float* src = Whh + (size_t)m * HID + k;
    f16x8 v;
#pragma unroll
    for (int j = 0; j < 8; ++j) v[j] = (f16)src[j];
    *(f16x8*)(frag + (size_t)id * 8) = v;
}

__device__ __forceinline__ float fast_tanh(float v) {
    v = fminf(fmaxf(v, -15.f), 15.f);
    float e = __expf(2.f * v);
    return (e - 1.f) * __builtin_amdgcn_rcpf(e + 1.f);
}

__global__ __launch_bounds__(512)
__attribute__((amdgpu_waves_per_eu(2, 2)))
void rnn_cu(
    const f16* __restrict__ frag,   // W_hh A-frags (all 16 kk-blocks)
    f16* __restrict__ hG,           // final h, frag-blocked [64][16][64][8]
    const float* __restrict__ x,    // [B][T]
    const float* __restrict__ Whx,  // [H]
    const float* __restrict__ bh)   // [H]
{
    __shared__ f16 HB[2][8192];     // double-buffered h, B-frag layout, 32 KB

    const int tid  = threadIdx.x;
    const int w    = tid >> 6;       // wave = row-group of 64 rows
    const int lane = tid & 63;
    const int n    = lane & 15;      // batch col within group
    const int q    = lane >> 4;
    const int bg   = blockIdx.x;     // batch group: cols [bg*16, +16)

    f16* hb0 = &HB[0][0];

    // ---- h(0) = 0 (buffer 0 is read at s=0) ----
    {
        f16x8 z;
#pragma unroll
        for (int j = 0; j < 8; ++j) z[j] = (f16)0.f;
        *(f16x8*)&hb0[tid * 16]     = z;
        *(f16x8*)&hb0[tid * 16 + 8] = z;
    }

    const f16x8* A = (const f16x8*)frag;

    // ---- register W portion: kk 0..11, kk-major, static indices ----
    f16x8 Wr[KR * 4];
#pragma unroll
    for (int kk = 0; kk < KR; ++kk)
#pragma unroll
        for (int mt = 0; mt < 4; ++mt)
            Wr[kk * 4 + mt] = A[((w * 4 + mt) * 16 + kk) * 64 + lane];

    // per-wave base for the global-resident W tail (kk 12..15)
    const f16x8* Aw = A + ((size_t)(w * 4) * 16 + KR) * 64 + lane;

    __syncthreads();

    const int b = bg * 16 + n;
    const float* xp = x + (size_t)b * SEQT;

#pragma unroll 1
    for (int s = 0; s < SEQT; ++s) {
        const f16* hbr = hb0 + ((s & 1) << 13);          // read h(s)
        f16*       hbw = hb0 + (((s & 1) ^ 1) << 13);    // write h(s+1)

        // Anti-LICM clobbers: without these the compiler hoists 16 W frags
        // (64 regs) + 8 Whx/bh vectors (32 regs) out of the loop and spills.
        const float* wbp = Whx;
        const float* bbp = bh;
        const f16x8* Awp = Aw;
        asm volatile("" : "+v"(wbp), "+v"(bbp), "+v"(Awp));

        // step-top loads: latency hides under the MFMA phase below
        float xv = xp[s];
        f32x4 av[4];
#pragma unroll
        for (int mt = 0; mt < 4; ++mt) {
            int m0 = w * 64 + mt * 16 + q * 4;
            f32x4 w4 = *(const f32x4*)(wbp + m0);
            f32x4 b4 = *(const f32x4*)(bbp + m0);
#pragma unroll
            for (int r = 0; r < 4; ++r) av[mt][r] = b4[r] + w4[r] * xv;
        }

        f32x4 acc[4] = {{0,0,0,0},{0,0,0,0},{0,0,0,0},{0,0,0,0}};

        // phase 1: W from registers, h from LDS
#pragma unroll
        for (int kk = 0; kk < KR; ++kk) {
            f16x8 bf = *(const f16x8*)&hbr[(kk * 64 + lane) * 8];
#pragma unroll
            for (int mt = 0; mt < 4; ++mt)
                acc[mt] = __builtin_amdgcn_mfma_f32_16x16x32_f16(
                    Wr[kk * 4 + mt], bf, acc[mt], 0, 0, 0);
        }
        // phase 2: W tail from global (VMEM pipe, L1/L2-hit), h from LDS
#pragma unroll
        for (int kkl = 0; kkl < 4; ++kkl) {
            f16x8 bf = *(const f16x8*)&hbr[((KR + kkl) * 64 + lane) * 8];
#pragma unroll
            for (int mt = 0; mt < 4; ++mt) {
                f16x8 a = Awp[((size_t)mt * 16 + kkl) * 64];
                acc[mt] = __builtin_amdgcn_mfma_f32_16x16x32_f16(
                    a, bf, acc[mt], 0, 0, 0);
            }
        }

        // ---- epilogue: pure tanh + write h(s+1) in B-frag layout ----
        // C layout: col n = lane&15, row m = w*64 + mt*16 + q*4 + r.
#pragma unroll
        for (int mt = 0; mt < 4; ++mt) {
            f16x4 hv;
#pragma unroll
            for (int r = 0; r < 4; ++r)
                hv[r] = (f16)fast_tanh(acc[mt][r] + av[mt][r]);
            int kkd = w * 2 + (mt >> 1);
            int q2  = (mt & 1) * 2 + (q >> 1);
            int j0  = (q & 1) * 4;
            int off = (kkd * 64 + q2 * 16 + n) * 8 + j0;
            if (s < SEQT - 1) {
                *(f16x4*)&hbw[off] = hv;
            } else {
                *(f16x4*)(hG + (size_t)(((bg * 16 + kkd) * 64 + q2 * 16 + n) * 8 + j0)) = hv;
            }
        }

        __syncthreads();   // h(s+1) visible before next step's reads
    }
}

// out[b][o] = by[o] + sum_k Wyh[o][k] * h[b][k], h in frag-blocked layout.
__global__ __launch_bounds__(256) void y_kernel(
    const f16* __restrict__ h, const float* __restrict__ Wyh,
    const float* __restrict__ by, float* __restrict__ out)
{
    int id = blockIdx.x * blockDim.x + threadIdx.x;
    if (id >= BATCH * OUTD) return;
    int b = id / OUTD, o = id % OUTD;
    int bg = b >> 4, n = b & 15;
    const float* wrow = Wyh + (size_t)o * HID;
    float s = by[o];
    for (int kk = 0; kk < 16; ++kk)
#pragma unroll
        for (int q2 = 0; q2 < 4; ++q2) {
            f16x8 hv = *(const f16x8*)(h + (size_t)((bg * 16 + kk) * 64 + q2 * 16 + n) * 8);
            const float* wp = wrow + kk * 32 + q2 * 8;
#pragma unroll
            for (int j = 0; j < 8; ++j) s += wp[j] * (float)hv[j];
        }
    out[id] = s;
}

extern "C" void kernel_launch(void* const* d_in, const int* in_sizes, int n_in,
                              void* d_out, int out_size, void* d_ws, size_t ws_size,
                              hipStream_t stream) {
    const float* x   = (const float*)d_in[0];
    const float* Whx = (const float*)d_in[1];
    const float* Whh = (const float*)d_in[2];
    const float* Wyh = (const float*)d_in[3];
    const float* bh  = (const float*)d_in[4];
    const float* by  = (const float*)d_in[5];
    float* out = (float*)d_out;

    char* ws   = (char*)d_ws;
    f16*  hG   = (f16*)ws;                       // 1 MB
    f16*  frag = (f16*)(ws + (2 << 20));         // 512 KB

    wconv_kernel<<<128, 256, 0, stream>>>(Whh, frag);
    rnn_cu<<<64, 512, 0, stream>>>(frag, hG, x, Whx, bh);
    y_kernel<<<(BATCH * OUTD + 255) / 256, 256, 0, stream>>>(hG, Wyh, by, out);
}

// Round 2
// 1462.440 us; speedup vs baseline: 1.1993x; 1.1993x over previous
//
#include <hip/hip_runtime.h>

// VanillaRNN: BATCH=1024, SEQ=512, HID=512, OUT=10
// h <- tanh(W_hh @ h + W_hx x_t + b_h), 512 steps, then y = W_yh h + b_y.
//
// Round 6: R5's counters showed the W-tail-from-global move was a pure
// latency loss (+2150 cyc/step; L2-resident per FETCH_SIZE but 2 waves/SIMD
// can't hide VMEM latency), while its dbuf/single-barrier/top-load changes
// were sound. Recombine:
//   * W tail (kk 12..15) back in LDS WL (R4's 1276us config) -> DS pipe,
//     short latency, overlaps MFMA.
//   * HB double-buffered -> ONE __syncthreads per step (R5-validated).
//   * x/Whx/bh loads at step top -> L1-hit latency hides under the 16-kk
//     MFMA phase instead of sitting after the barrier (R5-validated).
//   * LDS = 128K (WL) + 32K (HB dbuf) = 163840 B, the full 160 KiB pool.
//
// ws: [0,1MB) hG (final h, frag-blocked) | [2MB,2.5MB) W A-frags.

#define BATCH 1024
#define SEQT  512
#define HID   512
#define OUTD  10
#define KR    12   // kk-blocks (of K=32) in registers: K=384
#define NKK   16

typedef _Float16 f16;
typedef _Float16 f16x8 __attribute__((ext_vector_type(8)));
typedef _Float16 f16x4 __attribute__((ext_vector_type(4)));
typedef float    f32x4 __attribute__((ext_vector_type(4)));

// W_hh fp32 [H][H] -> fp16 A-fragment layout:
// entry ((g*4+mt)*16+kk)*64+lane = f16x8 of A[m][k],
// m = g*64+mt*16+(lane&15), k = kk*32+((lane>>4)&3)*8+j.
__global__ void wconv_kernel(const float* __restrict__ Whh, f16* __restrict__ frag) {
    int id = blockIdx.x * blockDim.x + threadIdx.x;   // 0..32767
    int lane = id & 63;
    int kk   = (id >> 6) & 15;
    int mt   = (id >> 10) & 3;
    int g    = id >> 12;
    int m = g * 64 + mt * 16 + (lane & 15);
    int k = kk * 32 + ((lane >> 4) & 3) * 8;
    const float* src = Whh + (size_t)m * HID + k;
    f16x8 v;
#pragma unroll
    for (int j = 0; j < 8; ++j) v[j] = (f16)src[j];
    *(f16x8*)(frag + (size_t)id * 8) = v;
}

__device__ __forceinline__ float fast_tanh(float v) {
    v = fminf(fmaxf(v, -15.f), 15.f);
    float e = __expf(2.f * v);
    return (e - 1.f) * __builtin_amdgcn_rcpf(e + 1.f);
}

__global__ __launch_bounds__(512)
__attribute__((amdgpu_waves_per_eu(2, 2)))
void rnn_cu(
    const f16* __restrict__ frag,   // W_hh A-frags (all 16 kk-blocks)
    f16* __restrict__ hG,           // final h, frag-blocked [64][16][64][8]
    const float* __restrict__ x,    // [B][T]
    const float* __restrict__ Whx,  // [H]
    const float* __restrict__ bh)   // [H]
{
    // HB first: its ds offsets (<32 KB) keep short addressing; WL spans the
    // rest of the 160 KiB pool.
    __shared__ f16 HB[2][8192];     // double-buffered h, B-frag layout, 32 KB
    __shared__ f16 WL[65536];       // W A-frags kk 12..15, 128 KB

    const int tid  = threadIdx.x;
    const int w    = tid >> 6;       // wave = row-group of 64 rows
    const int lane = tid & 63;
    const int n    = lane & 15;      // batch col within group
    const int q    = lane >> 4;
    const int bg   = blockIdx.x;     // batch group: cols [bg*16, +16)

    f16* hb0 = &HB[0][0];

    // ---- h(0) = 0 (buffer 0 is read at s=0) ----
    {
        f16x8 z;
#pragma unroll
        for (int j = 0; j < 8; ++j) z[j] = (f16)0.f;
        *(f16x8*)&hb0[tid * 16]     = z;
        *(f16x8*)&hb0[tid * 16 + 8] = z;
    }

    const f16x8* A = (const f16x8*)frag;

    // ---- LDS W portion: wave w stages its (mt, kk 12..15) frags ----
#pragma unroll
    for (int mt = 0; mt < 4; ++mt)
#pragma unroll
        for (int kkl = 0; kkl < 4; ++kkl) {
            int e = ((w * 4 + mt) * 4 + kkl) * 64 + lane;
            *(f16x8*)&WL[e * 8] = A[((w * 4 + mt) * 16 + (KR + kkl)) * 64 + lane];
        }

    // ---- register W portion: kk 0..11, kk-major, static indices ----
    f16x8 Wr[KR * 4];
#pragma unroll
    for (int kk = 0; kk < KR; ++kk)
#pragma unroll
        for (int mt = 0; mt < 4; ++mt)
            Wr[kk * 4 + mt] = A[((w * 4 + mt) * 16 + kk) * 64 + lane];

    __syncthreads();

    const int b = bg * 16 + n;
    const float* xp = x + (size_t)b * SEQT;

#pragma unroll 1
    for (int s = 0; s < SEQT; ++s) {
        const f16* hbr = hb0 + ((s & 1) << 13);          // read h(s)
        f16*       hbw = hb0 + (((s & 1) ^ 1) << 13);    // write h(s+1)

        // Anti-LICM clobbers: without these the compiler hoists 8 Whx/bh
        // vectors (32 regs) out of the loop and spills (R3's failure mode).
        const float* wbp = Whx;
        const float* bbp = bh;
        asm volatile("" : "+v"(wbp), "+v"(bbp));

        // step-top loads: L1-hit latency hides under the MFMA phase below
        float xv = xp[s];
        f32x4 av[4];
#pragma unroll
        for (int mt = 0; mt < 4; ++mt) {
            int m0 = w * 64 + mt * 16 + q * 4;
            f32x4 w4 = *(const f32x4*)(wbp + m0);
            f32x4 b4 = *(const f32x4*)(bbp + m0);
#pragma unroll
            for (int r = 0; r < 4; ++r) av[mt][r] = b4[r] + w4[r] * xv;
        }

        f32x4 acc[4] = {{0,0,0,0},{0,0,0,0},{0,0,0,0},{0,0,0,0}};

        // phase 1: W from registers, h from LDS
#pragma unroll
        for (int kk = 0; kk < KR; ++kk) {
            f16x8 bf = *(const f16x8*)&hbr[(kk * 64 + lane) * 8];
#pragma unroll
            for (int mt = 0; mt < 4; ++mt)
                acc[mt] = __builtin_amdgcn_mfma_f32_16x16x32_f16(
                    Wr[kk * 4 + mt], bf, acc[mt], 0, 0, 0);
        }
        // phase 2: W from LDS, h from LDS
#pragma unroll
        for (int kkl = 0; kkl < 4; ++kkl) {
            f16x8 bf = *(const f16x8*)&hbr[((KR + kkl) * 64 + lane) * 8];
#pragma unroll
            for (int mt = 0; mt < 4; ++mt) {
                f16x8 a = *(const f16x8*)&WL[(((w * 4 + mt) * 4 + kkl) * 64 + lane) * 8];
                acc[mt] = __builtin_amdgcn_mfma_f32_16x16x32_f16(
                    a, bf, acc[mt], 0, 0, 0);
            }
        }

        // ---- epilogue: pure tanh + write h(s+1) in B-frag layout ----
        // C layout: col n = lane&15, row m = w*64 + mt*16 + q*4 + r.
#pragma unroll
        for (int mt = 0; mt < 4; ++mt) {
            f16x4 hv;
#pragma unroll
            for (int r = 0; r < 4; ++r)
                hv[r] = (f16)fast_tanh(acc[mt][r] + av[mt][r]);
            int kkd = w * 2 + (mt >> 1);
            int q2  = (mt & 1) * 2 + (q >> 1);
            int j0  = (q & 1) * 4;
            int off = (kkd * 64 + q2 * 16 + n) * 8 + j0;
            if (s < SEQT - 1) {
                *(f16x4*)&hbw[off] = hv;
            } else {
                *(f16x4*)(hG + (size_t)(((bg * 16 + kkd) * 64 + q2 * 16 + n) * 8 + j0)) = hv;
            }
        }

        __syncthreads();   // h(s+1) visible before next step's reads
    }
}

// out[b][o] = by[o] + sum_k Wyh[o][k] * h[b][k], h in frag-blocked layout.
__global__ __launch_bounds__(256) void y_kernel(
    const f16* __restrict__ h, const float* __restrict__ Wyh,
    const float* __restrict__ by, float* __restrict__ out)
{
    int id = blockIdx.x * blockDim.x + threadIdx.x;
    if (id >= BATCH * OUTD) return;
    int b = id / OUTD, o = id % OUTD;
    int bg = b >> 4, n = b & 15;
    const float* wrow = Wyh + (size_t)o * HID;
    float s = by[o];
    for (int kk = 0; kk < 16; ++kk)
#pragma unroll
        for (int q2 = 0; q2 < 4; ++q2) {
            f16x8 hv = *(const f16x8*)(h + (size_t)((bg * 16 + kk) * 64 + q2 * 16 + n) * 8);
            const float* wp = wrow + kk * 32 + q2 * 8;
#pragma unroll
            for (int j = 0; j < 8; ++j) s += wp[j] * (float)hv[j];
        }
    out[id] = s;
}

extern "C" void kernel_launch(void* const* d_in, const int* in_sizes, int n_in,
                              void* d_out, int out_size, void* d_ws, size_t ws_size,
                              hipStream_t stream) {
    const float* x   = (const float*)d_in[0];
    const float* Whx = (const float*)d_in[1];
    const float* Whh = (const float*)d_in[2];
    const float* Wyh = (const float*)d_in[3];
    const float* bh  = (const float*)d_in[4];
    const float* by  = (const float*)d_in[5];
    float* out = (float*)d_out;

    char* ws   = (char*)d_ws;
    f16*  hG   = (f16*)ws;                       // 1 MB
    f16*  frag = (f16*)(ws + (2 << 20));         // 512 KB

    wconv_kernel<<<128, 256, 0, stream>>>(Whh, frag);
    rnn_cu<<<64, 512, 0, stream>>>(frag, hG, x, Whx, bh);
    y_kernel<<<(BATCH * OUTD + 255) / 256, 256, 0, stream>>>(hG, Wyh, by, out);
}

// Round 3
// 1332.935 us; speedup vs baseline: 1.3158x; 1.0972x over previous
//
#include <hip/hip_runtime.h>

// VanillaRNN: BATCH=1024, SEQ=512, HID=512, OUT=10
// h <- tanh(W_hh @ h + W_hx x_t + b_h), 512 steps, then y = W_yh h + b_y.
//
// Round 7: R4/R5/R6 triangulation says the regression mechanism was
// REGISTER PRESSURE, not barrier structure: holding av[16] f32 live across
// the MFMA phase (R5/R6) killed the scheduler's ability to pipeline the
// ds_read stream (the real bottleneck: 256 ds_read_b128/CU/step ~ 3100cyc).
// So: keep R4's register slack, remove the per-step global loads by
// hoisting Whx/bh as f16 (16 VGPRs total, consumed via v_fma_mix so no
// f32-cvt hoisting), and re-apply dbuf+single-barrier (now pressure-safe).
//   * epilogue is pure VALU tanh + ds_write: zero VMEM in the step loop
//     except the 1-dword x load at step top (hidden under full phase).
//   * LDS = 128K WL + 32K HB dbuf = 163840 B (full pool, 1 WG/CU).
//
// ws: [0,1MB) hG (final h, frag-blocked) | [2MB,2.5MB) W A-frags.

#define BATCH 1024
#define SEQT  512
#define HID   512
#define OUTD  10
#define KR    12   // kk-blocks (of K=32) in registers: K=384
#define NKK   16

typedef _Float16 f16;
typedef _Float16 f16x8 __attribute__((ext_vector_type(8)));
typedef _Float16 f16x4 __attribute__((ext_vector_type(4)));
typedef float    f32x4 __attribute__((ext_vector_type(4)));

// W_hh fp32 [H][H] -> fp16 A-fragment layout:
// entry ((g*4+mt)*16+kk)*64+lane = f16x8 of A[m][k],
// m = g*64+mt*16+(lane&15), k = kk*32+((lane>>4)&3)*8+j.
__global__ void wconv_kernel(const float* __restrict__ Whh, f16* __restrict__ frag) {
    int id = blockIdx.x * blockDim.x + threadIdx.x;   // 0..32767
    int lane = id & 63;
    int kk   = (id >> 6) & 15;
    int mt   = (id >> 10) & 3;
    int g    = id >> 12;
    int m = g * 64 + mt * 16 + (lane & 15);
    int k = kk * 32 + ((lane >> 4) & 3) * 8;
    const float* src = Whh + (size_t)m * HID + k;
    f16x8 v;
#pragma unroll
    for (int j = 0; j < 8; ++j) v[j] = (f16)src[j];
    *(f16x8*)(frag + (size_t)id * 8) = v;
}

__device__ __forceinline__ float fast_tanh(float v) {
    v = fminf(fmaxf(v, -15.f), 15.f);
    float e = __expf(2.f * v);
    return (e - 1.f) * __builtin_amdgcn_rcpf(e + 1.f);
}

__global__ __launch_bounds__(512)
__attribute__((amdgpu_waves_per_eu(2, 2)))
void rnn_cu(
    const f16* __restrict__ frag,   // W_hh A-frags (all 16 kk-blocks)
    f16* __restrict__ hG,           // final h, frag-blocked [64][16][64][8]
    const float* __restrict__ x,    // [B][T]
    const float* __restrict__ Whx,  // [H]
    const float* __restrict__ bh)   // [H]
{
    // HB first: short ds offsets (<32 KB) with lane-only addressing.
    __shared__ f16 HB[2][8192];     // double-buffered h, B-frag layout, 32 KB
    __shared__ f16 WL[65536];       // W A-frags kk 12..15, 128 KB

    const int tid  = threadIdx.x;
    const int w    = tid >> 6;       // wave = row-group of 64 rows
    const int lane = tid & 63;
    const int n    = lane & 15;      // batch col within group
    const int q    = lane >> 4;
    const int bg   = blockIdx.x;     // batch group: cols [bg*16, +16)

    // ---- h(0) = 0 (buffer 0 is read at s=0) ----
    {
        f16x8 z;
#pragma unroll
        for (int j = 0; j < 8; ++j) z[j] = (f16)0.f;
        *(f16x8*)&HB[0][tid * 16]     = z;
        *(f16x8*)&HB[0][tid * 16 + 8] = z;
    }

    const f16x8* A = (const f16x8*)frag;

    // ---- LDS W portion: wave w stages its (mt, kk 12..15) frags ----
#pragma unroll
    for (int mt = 0; mt < 4; ++mt)
#pragma unroll
        for (int kkl = 0; kkl < 4; ++kkl) {
            int e = ((w * 4 + mt) * 4 + kkl) * 64 + lane;
            *(f16x8*)&WL[e * 8] = A[((w * 4 + mt) * 16 + (KR + kkl)) * 64 + lane];
        }

    // ---- register W portion: kk 0..11, kk-major, static indices ----
    f16x8 Wr[KR * 4];
#pragma unroll
    for (int kk = 0; kk < KR; ++kk)
#pragma unroll
        for (int mt = 0; mt < 4; ++mt)
            Wr[kk * 4 + mt] = A[((w * 4 + mt) * 16 + kk) * 64 + lane];

    // ---- hoist Whx/bh ONCE as f16 (16 VGPRs total; consumed via fma_mix,
    //      so no f32 conversions exist for LICM to hoist) ----
    f16x4 wx_h[4], bh_h[4];
#pragma unroll
    for (int mt = 0; mt < 4; ++mt) {
        int m0 = w * 64 + mt * 16 + q * 4;
        f32x4 w4 = *(const f32x4*)(Whx + m0);
        f32x4 b4 = *(const f32x4*)(bh + m0);
#pragma unroll
        for (int r = 0; r < 4; ++r) {
            wx_h[mt][r] = (f16)w4[r];
            bh_h[mt][r] = (f16)b4[r];
        }
    }

    __syncthreads();

    const int b = bg * 16 + n;
    const float* xp = x + (size_t)b * SEQT;

#pragma unroll 1
    for (int s = 0; s < SEQT; ++s) {
        const f16* hbr = &HB[s & 1][0];          // read h(s)
        f16*       hbw = &HB[(s & 1) ^ 1][0];    // write h(s+1)

        // only VMEM op in the loop: 1 dword, hidden under the whole phase
        float xv = xp[s];

        f32x4 acc[4] = {{0,0,0,0},{0,0,0,0},{0,0,0,0},{0,0,0,0}};

        // phase 1: W from registers, h from LDS
#pragma unroll
        for (int kk = 0; kk < KR; ++kk) {
            f16x8 bf = *(const f16x8*)&hbr[(kk * 64 + lane) * 8];
#pragma unroll
            for (int mt = 0; mt < 4; ++mt)
                acc[mt] = __builtin_amdgcn_mfma_f32_16x16x32_f16(
                    Wr[kk * 4 + mt], bf, acc[mt], 0, 0, 0);
        }
        // phase 2: W from LDS, h from LDS
#pragma unroll
        for (int kkl = 0; kkl < 4; ++kkl) {
            f16x8 bf = *(const f16x8*)&hbr[((KR + kkl) * 64 + lane) * 8];
#pragma unroll
            for (int mt = 0; mt < 4; ++mt) {
                f16x8 a = *(const f16x8*)&WL[(((w * 4 + mt) * 4 + kkl) * 64 + lane) * 8];
                acc[mt] = __builtin_amdgcn_mfma_f32_16x16x32_f16(
                    a, bf, acc[mt], 0, 0, 0);
            }
        }

        // ---- epilogue: pure VALU tanh + ds_write h(s+1) in B-frag layout ----
        // C layout: col n = lane&15, row m = w*64 + mt*16 + q*4 + r.
#pragma unroll
        for (int mt = 0; mt < 4; ++mt) {
            f16x4 hv;
#pragma unroll
            for (int r = 0; r < 4; ++r) {
                float pre = fmaf((float)wx_h[mt][r], xv, acc[mt][r])
                          + (float)bh_h[mt][r];
                hv[r] = (f16)fast_tanh(pre);
            }
            int kkd = w * 2 + (mt >> 1);
            int q2  = (mt & 1) * 2 + (q >> 1);
            int j0  = (q & 1) * 4;
            int off = (kkd * 64 + q2 * 16 + n) * 8 + j0;
            if (s < SEQT - 1) {
                *(f16x4*)&hbw[off] = hv;
            } else {
                *(f16x4*)(hG + (size_t)(((bg * 16 + kkd) * 64 + q2 * 16 + n) * 8 + j0)) = hv;
            }
        }

        __syncthreads();   // h(s+1) visible before next step's reads
    }
}

// out[b][o] = by[o] + sum_k Wyh[o][k] * h[b][k], h in frag-blocked layout.
__global__ __launch_bounds__(256) void y_kernel(
    const f16* __restrict__ h, const float* __restrict__ Wyh,
    const float* __restrict__ by, float* __restrict__ out)
{
    int id = blockIdx.x * blockDim.x + threadIdx.x;
    if (id >= BATCH * OUTD) return;
    int b = id / OUTD, o = id % OUTD;
    int bg = b >> 4, n = b & 15;
    const float* wrow = Wyh + (size_t)o * HID;
    float s = by[o];
    for (int kk = 0; kk < 16; ++kk)
#pragma unroll
        for (int q2 = 0; q2 < 4; ++q2) {
            f16x8 hv = *(const f16x8*)(h + (size_t)((bg * 16 + kk) * 64 + q2 * 16 + n) * 8);
            const float* wp = wrow + kk * 32 + q2 * 8;
#pragma unroll
            for (int j = 0; j < 8; ++j) s += wp[j] * (float)hv[j];
        }
    out[id] = s;
}

extern "C" void kernel_launch(void* const* d_in, const int* in_sizes, int n_in,
                              void* d_out, int out_size, void* d_ws, size_t ws_size,
                              hipStream_t stream) {
    const float* x   = (const float*)d_in[0];
    const float* Whx = (const float*)d_in[1];
    const float* Whh = (const float*)d_in[2];
    const float* Wyh = (const float*)d_in[3];
    const float* bh  = (const float*)d_in[4];
    const float* by  = (const float*)d_in[5];
    float* out = (float*)d_out;

    char* ws   = (char*)d_ws;
    f16*  hG   = (f16*)ws;                       // 1 MB
    f16*  frag = (f16*)(ws + (2 << 20));         // 512 KB

    wconv_kernel<<<128, 256, 0, stream>>>(Whh, frag);
    rnn_cu<<<64, 512, 0, stream>>>(frag, hG, x, Whx, bh);
    y_kernel<<<(BATCH * OUTD + 255) / 256, 256, 0, stream>>>(hG, Wyh, by, out);
}